// Round 6
// baseline (662.251 us; speedup 1.0000x reference)
//
#include <hip/hip_runtime.h>

#define N 32768
#define F 768
#define C 64
#define P 8192
#define TAU 1e-3f

typedef __attribute__((ext_vector_type(8))) short short8;
typedef __attribute__((ext_vector_type(4))) float f32x4;

// ---------------- workspace layout (float offsets) ----------------
#define WS_CNT    0                        // cnT   fp32 [C][P] k-major (recheck+loss gather)
#define WS_CC     (WS_CNT + C*P)           // cc    [P]
#define WS_ZQT    (WS_CC + P)              // zqT   fp32 [C][N] k-major (loss+recheck)
#define WS_CODEST (WS_ZQT + C*N)           // hole: w_in splits + d12 live here
#define WS_WIH    WS_CODEST                // w_in hi bf16 [C][F]
#define WS_WIM    (WS_WIH + (C*F)/2)       // w_in mid bf16 [C][F]
#define WS_WIL    (WS_WIM + (C*F)/2)       // w_in lo bf16 [C][F]
#define WS_D12    (WS_WIL + (C*F)/2)       // float4 [8][N] (s1,s2,i1_bits,pad) - in hole
// WS_D12 end = WS_CODEST + 73728 + 8*N*4 = WS_CODEST + 1122304 < WS_CODEST + C*N ✓
#define WS_IDX    (WS_CODEST + C*N)        // idx   [N] int
#define WS_QN     (WS_IDX + N)             // queue count (int)
#define WS_ACC    (WS_QN + 1)              // loss accumulator
#define WS_QLIST  (WS_ACC + 1)             // queue [N] int
#define WS_CNH    ((WS_QLIST + N + 3) & ~3)  // cn_hi bf16 [P][C] row-major
#define WS_CNL    (WS_CNH + (C*P)/2)       // cn_lo bf16 [P][C]
#define WS_ZQH    (WS_CNL + (C*P)/2)       // zq_hi bf16 [N][C] row-major
#define WS_ZQL    (WS_ZQH + (C*N)/2)       // zq_lo bf16 [N][C]
#define WS_WOH    (WS_ZQL + (C*N)/2)       // w_out hi bf16 [F][C]
#define WS_WOL    (WS_WOH + (F*C)/2)       // w_out lo bf16 [F][C]
// end ≈ 29.8 MB

#define OUT_LOSS_OFF (N*F)
#define OUT_IDX_OFF  (N*F + 1)

__device__ inline unsigned short f2bf(float x) {   // fp32 -> bf16 RNE
    union { float f; unsigned u; } v; v.f = x;
    unsigned r = v.u + 0x7fffu + ((v.u >> 16) & 1u);
    return (unsigned short)(r >> 16);
}
__device__ inline float bf2f(unsigned short b) {
    union { unsigned u; float f; } v; v.u = ((unsigned)b) << 16;
    return v.f;
}

union U32S8 { unsigned u[4]; short8 s; };

// 8 consecutive fp32 -> 3 bf16 levels (trunc split)
__device__ inline void split3x8(const float* xp, short8& h, short8& m, short8& l) {
    U32S8 hh, mm, ll;
#pragma unroll
    for (int i = 0; i < 4; ++i) {
        float xa = xp[2 * i], xb = xp[2 * i + 1];
        unsigned ha = __float_as_uint(xa) & 0xffff0000u;
        unsigned hb = __float_as_uint(xb) & 0xffff0000u;
        hh.u[i] = (ha >> 16) | hb;
        float ra = xa - __uint_as_float(ha), rb = xb - __uint_as_float(hb);
        unsigned ma = __float_as_uint(ra) & 0xffff0000u;
        unsigned mb = __float_as_uint(rb) & 0xffff0000u;
        mm.u[i] = (ma >> 16) | mb;
        float sa = ra - __uint_as_float(ma), sb = rb - __uint_as_float(mb);
        ll.u[i] = ((__float_as_uint(sa) & 0xffff0000u) >> 16) |
                  (__float_as_uint(sb) & 0xffff0000u);
    }
    h = hh.s; m = mm.s; l = ll.s;
}

// ---------------- K1: normalize codebook -> cnT [C][P], cc, cn_hi/lo [P][C] ----
__global__ __launch_bounds__(256) void k1_norm_codebook(
    const float* __restrict__ cb, float* __restrict__ cnT, float* __restrict__ cc,
    unsigned short* __restrict__ cnh, unsigned short* __restrict__ cnl) {
    int p = blockIdx.x * 256 + threadIdx.x;   // one thread per page
    const float4* cb4 = (const float4*)(cb + (size_t)p * C);
    float4 v[16];
    float ss = 0.f;
#pragma unroll
    for (int i = 0; i < 16; ++i) {
        v[i] = cb4[i];
        ss += v[i].x * v[i].x + v[i].y * v[i].y + v[i].z * v[i].z + v[i].w * v[i].w;
    }
    float nrm = sqrtf(ss);
    float s2 = 0.f;
    unsigned short hb[64], lb[64];
#pragma unroll
    for (int i = 0; i < 16; ++i) {
        float c4[4] = {v[i].x / nrm, v[i].y / nrm, v[i].z / nrm, v[i].w / nrm};
#pragma unroll
        for (int j = 0; j < 4; ++j) {
            cnT[(size_t)(i * 4 + j) * P + p] = c4[j];
            s2 += c4[j] * c4[j];
            unsigned short h = f2bf(c4[j]);
            hb[i * 4 + j] = h;
            lb[i * 4 + j] = f2bf(c4[j] - bf2f(h));
        }
    }
    cc[p] = s2;
#pragma unroll
    for (int i = 0; i < 8; ++i) {
        uint4 hv, lv;
        hv.x = (unsigned)hb[i*8+0] | ((unsigned)hb[i*8+1] << 16);
        hv.y = (unsigned)hb[i*8+2] | ((unsigned)hb[i*8+3] << 16);
        hv.z = (unsigned)hb[i*8+4] | ((unsigned)hb[i*8+5] << 16);
        hv.w = (unsigned)hb[i*8+6] | ((unsigned)hb[i*8+7] << 16);
        lv.x = (unsigned)lb[i*8+0] | ((unsigned)lb[i*8+1] << 16);
        lv.y = (unsigned)lb[i*8+2] | ((unsigned)lb[i*8+3] << 16);
        lv.z = (unsigned)lb[i*8+4] | ((unsigned)lb[i*8+5] << 16);
        lv.w = (unsigned)lb[i*8+6] | ((unsigned)lb[i*8+7] << 16);
        *(uint4*)&cnh[(size_t)p * 64 + i * 8] = hv;
        *(uint4*)&cnl[(size_t)p * 64 + i * 8] = lv;
    }
}

// ---------------- K2p: w_in -> 3-level bf16 split [C][F] ----------------
__global__ __launch_bounds__(256) void k2_prep(
    const float* __restrict__ w_in, unsigned short* __restrict__ wih,
    unsigned short* __restrict__ wim, unsigned short* __restrict__ wil) {
    int i = blockIdx.x * 256 + threadIdx.x;   // C*F = 49152
    float x = w_in[i];
    unsigned hu = __float_as_uint(x) & 0xffff0000u;
    float r1 = x - __uint_as_float(hu);
    unsigned mu = __float_as_uint(r1) & 0xffff0000u;
    float r2 = r1 - __uint_as_float(mu);
    wih[i] = (unsigned short)(hu >> 16);
    wim[i] = (unsigned short)(mu >> 16);
    wil[i] = f2bf(r2);
}

// ---------------- K2: zq = normalize(z @ w_in^T + b_in), K-split x2 MFMA ----------
// 128 thr = 2 waves/block; wave w covers k in [w*384,(w+1)*384). 4096 waves total
// = 4 waves/SIMD (was 2: L2-load latency exposed). Partials combined via LDS.
__global__ __launch_bounds__(128) void k2_project_mfma(
    const float* __restrict__ z,
    const unsigned short* __restrict__ wih, const unsigned short* __restrict__ wim,
    const unsigned short* __restrict__ wil, const float* __restrict__ b_in,
    float* __restrict__ zqT, unsigned short* __restrict__ zqh,
    unsigned short* __restrict__ zql) {
    __shared__ float lacc[2][16][68];   // pad 68: float4-aligned rows, <=2-way banks
    int tid = threadIdx.x;
    int w = tid >> 6, lane = tid & 63;
    int col = lane & 15, quad = lane >> 4;
    int wrow = blockIdx.x * 16;

    f32x4 acc[4];
#pragma unroll
    for (int nt = 0; nt < 4; ++nt) acc[nt] = (f32x4){0.f, 0.f, 0.f, 0.f};

    const float* zrow = z + (size_t)(wrow + col) * F + quad * 8;
#pragma unroll 2
    for (int kt = w * 12; kt < w * 12 + 12; ++kt) {
        float xz[8];
        *(float4*)&xz[0] = *(const float4*)&zrow[kt * 32];
        *(float4*)&xz[4] = *(const float4*)&zrow[kt * 32 + 4];
        short8 ah, am, al;
        split3x8(xz, ah, am, al);
#pragma unroll
        for (int nt = 0; nt < 4; ++nt) {
            size_t bo = (size_t)(nt * 16 + col) * F + kt * 32 + quad * 8;
            short8 bh = *(const short8*)&wih[bo];
            short8 bm = *(const short8*)&wim[bo];
            short8 bl = *(const short8*)&wil[bo];
            acc[nt] = __builtin_amdgcn_mfma_f32_16x16x32_bf16(ah, bh, acc[nt], 0, 0, 0);
            acc[nt] = __builtin_amdgcn_mfma_f32_16x16x32_bf16(ah, bm, acc[nt], 0, 0, 0);
            acc[nt] = __builtin_amdgcn_mfma_f32_16x16x32_bf16(am, bh, acc[nt], 0, 0, 0);
            acc[nt] = __builtin_amdgcn_mfma_f32_16x16x32_bf16(ah, bl, acc[nt], 0, 0, 0);
            acc[nt] = __builtin_amdgcn_mfma_f32_16x16x32_bf16(al, bh, acc[nt], 0, 0, 0);
            acc[nt] = __builtin_amdgcn_mfma_f32_16x16x32_bf16(am, bm, acc[nt], 0, 0, 0);
        }
    }
    // partials -> LDS: lacc[w][row=quad*4+s][code=nt*16+col]
#pragma unroll
    for (int nt = 0; nt < 4; ++nt)
#pragma unroll
        for (int s = 0; s < 4; ++s)
            lacc[w][quad * 4 + s][nt * 16 + col] = acc[nt][s];
    __syncthreads();
    // combine: thread -> (row = tid>>3, codes cg*8..+8)
    int row = tid >> 3, cg = tid & 7;
    float y[8];
#pragma unroll
    for (int j = 0; j < 8; ++j) {
        int c = cg * 8 + j;
        y[j] = lacc[0][row][c] + lacc[1][row][c] + b_in[c];
    }
    float ssum = 0.f;
#pragma unroll
    for (int j = 0; j < 8; ++j) ssum += y[j] * y[j];
#pragma unroll
    for (int m = 1; m <= 4; m <<= 1) ssum += __shfl_xor(ssum, m);   // 8 lanes/row
    float nrm = sqrtf(ssum);
#pragma unroll
    for (int j = 0; j < 8; ++j) y[j] /= nrm;
    // zqh/zql: 8 codes per thread -> one uint4 each
    {
        unsigned hu[4], lu[4];
#pragma unroll
        for (int k = 0; k < 4; ++k) {
            unsigned short h0 = f2bf(y[2 * k]), h1 = f2bf(y[2 * k + 1]);
            unsigned short l0 = f2bf(y[2 * k] - bf2f(h0));
            unsigned short l1 = f2bf(y[2 * k + 1] - bf2f(h1));
            hu[k] = (unsigned)h0 | ((unsigned)h1 << 16);
            lu[k] = (unsigned)l0 | ((unsigned)l1 << 16);
        }
        size_t ro = (size_t)(wrow + row) * 64 + cg * 8;
        *(uint4*)&zqh[ro] = make_uint4(hu[0], hu[1], hu[2], hu[3]);
        *(uint4*)&zql[ro] = make_uint4(lu[0], lu[1], lu[2], lu[3]);
    }
    // zqT transpose via LDS (reuse lacc[0] after all combine reads done)
    __syncthreads();
#pragma unroll
    for (int j = 0; j < 8; ++j) lacc[0][row][cg * 8 + j] = y[j];
    __syncthreads();
    {
        int c = tid & 63, half = tid >> 6;   // wave0 rows 0-7, wave1 rows 8-15
        float t[8];
#pragma unroll
        for (int r = 0; r < 8; ++r) t[r] = lacc[0][half * 8 + r][c];
        float* dst = &zqT[(size_t)c * N + wrow + half * 8];
        *(float4*)&dst[0] = make_float4(t[0], t[1], t[2], t[3]);
        *(float4*)&dst[4] = make_float4(t[4], t[5], t[6], t[7]);
    }
}

// ---------------- K3: split-bf16 MFMA similarity + top-2, 64 rows/wave ----------------
// block = 4 waves covering 256 rows x 1024 pages (P/8); grid = 128 x 8 = 1024.
// each B ds_read feeds 24 MFMAs (was 12); update = 4 VALU/element via fmed3.
// VGPR ~160 -> launch_bounds(256,3): 12 waves/CU.
__global__ __launch_bounds__(256, 3) void k3_argmin_mfma(
    const unsigned short* __restrict__ zqh, const unsigned short* __restrict__ zql,
    const unsigned short* __restrict__ cnh, const unsigned short* __restrict__ cnl,
    float4* __restrict__ d12) {
    __shared__ unsigned short lfrag[8 * 4 * 64 * 8];   // [nt][f][slot][8] = 32 KB
    int tid = threadIdx.x;
    int w = tid >> 6, lane = tid & 63;
    int col = lane & 15, quad = lane >> 4;
    int rb = (blockIdx.x & 127) * 256;
    int ph = blockIdx.x >> 7;            // which eighth of P
    int wrow = rb + w * 64;              // wave: rows [wrow, wrow+64)
    int p0 = ph * (P / 8);

    short8 ah[4][2], al[4][2];
#pragma unroll
    for (int mm = 0; mm < 4; ++mm)
#pragma unroll
        for (int kf = 0; kf < 2; ++kf) {
            size_t off = (size_t)(wrow + mm * 16 + col) * 64 + kf * 32 + quad * 8;
            ah[mm][kf] = *(const short8*)&zqh[off];
            al[mm][kf] = *(const short8*)&zql[off];
        }

    float s1[16], s2[16]; int i1[16];    // r = mm*4+s
#pragma unroll
    for (int r = 0; r < 16; ++r) { s1[r] = -3.4e38f; s2[r] = -3.4e38f; i1[r] = 0; }

    int sq = (tid >> 4) & 3, scol = tid & 15, sf = w;
    const unsigned short* ssrc = (sf & 2) ? cnl : cnh;
    int skf = sf & 1;

    for (int pt = p0; pt < p0 + P / 8; pt += 128) {
        __syncthreads();
#pragma unroll
        for (int nt = 0; nt < 8; ++nt) {
            int p = pt + nt * 16 + scol;
            uint4 dv = *(const uint4*)&ssrc[(size_t)p * 64 + skf * 32 + sq * 8];
            *(uint4*)&lfrag[((nt * 4 + sf) * 64 + (tid & 63)) * 8] = dv;
        }
        __syncthreads();
#pragma unroll 1
        for (int nt = 0; nt < 8; ++nt) {
            short8 bh0 = *(const short8*)&lfrag[((nt * 4 + 0) * 64 + lane) * 8];
            short8 bh1 = *(const short8*)&lfrag[((nt * 4 + 1) * 64 + lane) * 8];
            short8 bl0 = *(const short8*)&lfrag[((nt * 4 + 2) * 64 + lane) * 8];
            short8 bl1 = *(const short8*)&lfrag[((nt * 4 + 3) * 64 + lane) * 8];
            int p = pt + nt * 16 + col;
#pragma unroll
            for (int mm = 0; mm < 4; ++mm) {
                f32x4 acc = {0.f, 0.f, 0.f, 0.f};
                acc = __builtin_amdgcn_mfma_f32_16x16x32_bf16(ah[mm][0], bh0, acc, 0, 0, 0);
                acc = __builtin_amdgcn_mfma_f32_16x16x32_bf16(ah[mm][1], bh1, acc, 0, 0, 0);
                acc = __builtin_amdgcn_mfma_f32_16x16x32_bf16(ah[mm][0], bl0, acc, 0, 0, 0);
                acc = __builtin_amdgcn_mfma_f32_16x16x32_bf16(ah[mm][1], bl1, acc, 0, 0, 0);
                acc = __builtin_amdgcn_mfma_f32_16x16x32_bf16(al[mm][0], bh0, acc, 0, 0, 0);
                acc = __builtin_amdgcn_mfma_f32_16x16x32_bf16(al[mm][1], bh1, acc, 0, 0, 0);
#pragma unroll
                for (int s = 0; s < 4; ++s) {
                    float sv = acc[s];
                    int r = mm * 4 + s;
                    bool gt = sv > s1[r];                    // strict >: first page wins
                    i1[r] = gt ? p : i1[r];
                    s2[r] = __builtin_amdgcn_fmed3f(s1[r], sv, s2[r]);  // = max(s2,min(s1,sv))
                    s1[r] = fmaxf(s1[r], sv);
                }
            }
        }
    }
#pragma unroll
    for (int r = 0; r < 16; ++r) {
        float a1v = s1[r], a2v = s2[r]; int ai = i1[r];
#pragma unroll
        for (int m = 1; m <= 8; m <<= 1) {
            float b1 = __shfl_xor(a1v, m); int bi = __shfl_xor(ai, m);
            float b2 = __shfl_xor(a2v, m);
            float n1 = fmaxf(a1v, b1);
            a2v = fmaxf(fminf(a1v, b1), fmaxf(a2v, b2));
            ai = (b1 > a1v) ? bi : ai;
            a1v = n1;
        }
        if (col == 0) {
            int row = wrow + (r >> 2) * 16 + quad * 4 + (r & 3);
            d12[ph * N + row] = make_float4(a1v, a2v, __int_as_float(ai), 0.f);
        }
    }
}

// ---------------- K3m: merge the eight P-parts, write idx, flag near-ties ----------
__global__ __launch_bounds__(256) void k3m_merge(
    const float4* __restrict__ d12, int* __restrict__ idx_ws, float* __restrict__ idx_out,
    int* __restrict__ qn, int* __restrict__ qlist) {
    int row = blockIdx.x * 256 + threadIdx.x;
    float4 a = d12[row];
    float m1 = a.x, m2 = a.y; int i1 = __float_as_int(a.z);
#pragma unroll
    for (int ph = 1; ph < 8; ++ph) {
        float4 b = d12[ph * N + row];
        m2 = fmaxf(fminf(m1, b.x), fmaxf(m2, b.y));
        if (b.x > m1) { i1 = __float_as_int(b.z); m1 = b.x; }
    }
    idx_ws[row] = i1;
    idx_out[row] = (float)i1;
    if (m1 - m2 < 0.5f * TAU + 2e-6f) {
        int qi = atomicAdd(qn, 1);
        qlist[qi] = row;
    }
}

// ---------------- K3r: exact fp32 argmin for flagged rows, 8 entries/block ----------
// one cnT sweep (2 MB L2) serves 8 rows -> L2 traffic / 8 vs single-entry version.
__global__ __launch_bounds__(256) void k3_recheck(
    const float* __restrict__ zqT, const float* __restrict__ cnT,
    const float* __restrict__ cc, const int* __restrict__ qn,
    const int* __restrict__ qlist, int* __restrict__ idx_ws, float* __restrict__ idx_out) {
    __shared__ float zrT[64][8];         // [k][entry]
    __shared__ float bv[4][8];
    __shared__ int   bi[4][8];
    __shared__ int   rows[8];
    int tid = threadIdx.x, w = tid >> 6, lane = tid & 63;
    int nq = qn[0];
    for (int g = blockIdx.x * 8; g < nq; g += gridDim.x * 8) {
        int cnt = min(8, nq - g);
        __syncthreads();    // protect shared state from previous iteration readers
        if (tid < 8) rows[tid] = (tid < cnt) ? qlist[g + tid] : 0;
        __syncthreads();
        for (int i = tid; i < 8 * 64; i += 256) {
            int j = i & 7, k = i >> 3;
            zrT[k][j] = (j < cnt) ? zqT[(size_t)k * N + rows[j]] : 0.f;
        }
        __syncthreads();
        float best[8]; int bp[8];
#pragma unroll
        for (int j = 0; j < 8; ++j) { best[j] = 3.4e38f; bp[j] = 0; }
        for (int pb = w * 2048; pb < (w + 1) * 2048; pb += 64) {
            int p = pb + lane;
            float a[8];
#pragma unroll
            for (int j = 0; j < 8; ++j) a[j] = 0.f;
#pragma unroll 4
            for (int k = 0; k < 64; ++k) {
                float cv = cnT[(size_t)k * P + p];
                float4 z0 = *(const float4*)&zrT[k][0];
                float4 z1 = *(const float4*)&zrT[k][4];
                a[0] = fmaf(z0.x, cv, a[0]); a[1] = fmaf(z0.y, cv, a[1]);
                a[2] = fmaf(z0.z, cv, a[2]); a[3] = fmaf(z0.w, cv, a[3]);
                a[4] = fmaf(z1.x, cv, a[4]); a[5] = fmaf(z1.y, cv, a[5]);
                a[6] = fmaf(z1.z, cv, a[6]); a[7] = fmaf(z1.w, cv, a[7]);
            }
            float ccv = cc[p];
#pragma unroll
            for (int j = 0; j < 8; ++j) {
                float d = fmaf(a[j], -2.0f, ccv);
                if (d < best[j]) { best[j] = d; bp[j] = p; }   // p ascending: first wins
            }
        }
#pragma unroll
        for (int j = 0; j < 8; ++j) {
#pragma unroll
            for (int m = 1; m < 64; m <<= 1) {
                float ob = __shfl_xor(best[j], m); int op = __shfl_xor(bp[j], m);
                if (ob < best[j] || (ob == best[j] && op < bp[j])) { best[j] = ob; bp[j] = op; }
            }
        }
        if (lane == 0) {
#pragma unroll
            for (int j = 0; j < 8; ++j) { bv[w][j] = best[j]; bi[w][j] = bp[j]; }
        }
        __syncthreads();
        if (tid < cnt) {
            int j = tid;
            float b = bv[0][j]; int pi = bi[0][j];
#pragma unroll
            for (int ww = 1; ww < 4; ++ww)
                if (bv[ww][j] < b || (bv[ww][j] == b && bi[ww][j] < pi)) { b = bv[ww][j]; pi = bi[ww][j]; }
            idx_ws[rows[j]] = pi; idx_out[rows[j]] = (float)pi;
        }
    }
}

// ---------------- K3b: fused gather + loss (no codesT materialization) ----------
__global__ __launch_bounds__(256) void k3b_gather_loss(
    const float* __restrict__ cnT, const int* __restrict__ idx,
    const float* __restrict__ zqT, float* __restrict__ acc) {
    float s = 0.f;
    for (size_t i = (size_t)blockIdx.x * 256 + threadIdx.x; i < (size_t)C * N;
         i += (size_t)gridDim.x * 256) {
        int k = (int)(i >> 15);          // N = 2^15
        int r = (int)(i & (N - 1));
        float d = zqT[i] - cnT[(size_t)k * P + idx[r]];
        s = fmaf(d, d, s);
    }
#pragma unroll
    for (int off = 32; off > 0; off >>= 1) s += __shfl_xor(s, off);
    __shared__ float wsum[4];
    int lane = threadIdx.x & 63, wv = threadIdx.x >> 6;
    if (lane == 0) wsum[wv] = s;
    __syncthreads();
    if (threadIdx.x == 0) atomicAdd(acc, wsum[0] + wsum[1] + wsum[2] + wsum[3]);
}

// ---------------- K4p: w_out -> bf16 hi/lo [F][C] ----------------
__global__ __launch_bounds__(256) void k4_prep(
    const float* __restrict__ w_out, unsigned short* __restrict__ woh,
    unsigned short* __restrict__ wol) {
    int i = blockIdx.x * 256 + threadIdx.x;   // F*C = 49152
    float v = w_out[i];
    unsigned short h = f2bf(v);
    woh[i] = h;
    wol[i] = f2bf(v - bf2f(h));
}

// ---------------- K4: out = codes @ w_out^T + b_out, split-bf16 MFMA ----------------
__global__ __launch_bounds__(256) void k4_out_mfma(
    const unsigned short* __restrict__ cnh, const unsigned short* __restrict__ cnl,
    const unsigned short* __restrict__ woh, const unsigned short* __restrict__ wol,
    const int* __restrict__ idx, const float* __restrict__ b_out, float* __restrict__ out) {
    int tid = threadIdx.x;
    int w = tid >> 6, lane = tid & 63;
    int col = lane & 15, quad = lane >> 4;
    int rb = (blockIdx.x >> 2) * 64;
    int fb = (blockIdx.x & 3) * 192;
    int wrow = rb + w * 16;

    int pg = idx[wrow + col];            // A[m=col][k]: gather code page for this row
    short8 ah[2], al[2];
#pragma unroll
    for (int kf = 0; kf < 2; ++kf) {
        size_t off = (size_t)pg * 64 + kf * 32 + quad * 8;
        ah[kf] = *(const short8*)&cnh[off];
        al[kf] = *(const short8*)&cnl[off];
    }

    for (int ft = 0; ft < 12; ++ft) {
        int f0 = fb + ft * 16;
        size_t bo = (size_t)(f0 + col) * 64 + quad * 8;   // B[n=col][k]
        short8 bh0 = *(const short8*)&woh[bo];
        short8 bh1 = *(const short8*)&woh[bo + 32];
        short8 bl0 = *(const short8*)&wol[bo];
        short8 bl1 = *(const short8*)&wol[bo + 32];
        f32x4 acc = {0.f, 0.f, 0.f, 0.f};
        acc = __builtin_amdgcn_mfma_f32_16x16x32_bf16(ah[0], bh0, acc, 0, 0, 0);
        acc = __builtin_amdgcn_mfma_f32_16x16x32_bf16(ah[1], bh1, acc, 0, 0, 0);
        acc = __builtin_amdgcn_mfma_f32_16x16x32_bf16(ah[0], bl0, acc, 0, 0, 0);
        acc = __builtin_amdgcn_mfma_f32_16x16x32_bf16(ah[1], bl1, acc, 0, 0, 0);
        acc = __builtin_amdgcn_mfma_f32_16x16x32_bf16(al[0], bh0, acc, 0, 0, 0);
        acc = __builtin_amdgcn_mfma_f32_16x16x32_bf16(al[1], bh1, acc, 0, 0, 0);
        float bv = b_out[f0 + col];
#pragma unroll
        for (int s = 0; s < 4; ++s)
            out[(size_t)(wrow + quad * 4 + s) * F + f0 + col] = acc[s] + bv;
    }
}

// ---------------- K6: finalize loss ----------------
__global__ void k6_finalize(const float* __restrict__ acc, float* __restrict__ loss_out) {
    float m = acc[0] / (float)(C * N);
    loss_out[0] = 0.25f * m + m;   // BETA*mean + mean
}

extern "C" void kernel_launch(void* const* d_in, const int* in_sizes, int n_in,
                              void* d_out, int out_size, void* d_ws, size_t ws_size,
                              hipStream_t stream) {
    const float* z      = (const float*)d_in[0];
    const float* w_in   = (const float*)d_in[1];
    const float* b_in   = (const float*)d_in[2];
    const float* w_out  = (const float*)d_in[3];
    const float* b_out  = (const float*)d_in[4];
    const float* cb     = (const float*)d_in[5];
    float* out = (float*)d_out;
    float* ws  = (float*)d_ws;

    unsigned short* cnh = (unsigned short*)(ws + WS_CNH);
    unsigned short* cnl = (unsigned short*)(ws + WS_CNL);
    unsigned short* zqh = (unsigned short*)(ws + WS_ZQH);
    unsigned short* zql = (unsigned short*)(ws + WS_ZQL);
    unsigned short* woh = (unsigned short*)(ws + WS_WOH);
    unsigned short* wol = (unsigned short*)(ws + WS_WOL);
    unsigned short* wih = (unsigned short*)(ws + WS_WIH);
    unsigned short* wim = (unsigned short*)(ws + WS_WIM);
    unsigned short* wil = (unsigned short*)(ws + WS_WIL);

    hipMemsetAsync(ws + WS_QN, 0, 2 * sizeof(float), stream);   // qn + loss acc
    k1_norm_codebook<<<P / 256, 256, 0, stream>>>(cb, ws + WS_CNT, ws + WS_CC, cnh, cnl);
    k2_prep<<<C * F / 256, 256, 0, stream>>>(w_in, wih, wim, wil);
    k4_prep<<<F * C / 256, 256, 0, stream>>>(w_out, woh, wol);
    k2_project_mfma<<<N / 16, 128, 0, stream>>>(z, wih, wim, wil, b_in,
                                                ws + WS_ZQT, zqh, zql);
    k3_argmin_mfma<<<1024, 256, 0, stream>>>(zqh, zql, cnh, cnl, (float4*)(ws + WS_D12));
    k3m_merge<<<N / 256, 256, 0, stream>>>((const float4*)(ws + WS_D12),
                                           (int*)(ws + WS_IDX), out + OUT_IDX_OFF,
                                           (int*)(ws + WS_QN), (int*)(ws + WS_QLIST));
    k3_recheck<<<512, 256, 0, stream>>>(ws + WS_ZQT, ws + WS_CNT, ws + WS_CC,
                                        (const int*)(ws + WS_QN), (const int*)(ws + WS_QLIST),
                                        (int*)(ws + WS_IDX), out + OUT_IDX_OFF);
    k3b_gather_loss<<<2048, 256, 0, stream>>>(ws + WS_CNT, (const int*)(ws + WS_IDX),
                                              ws + WS_ZQT, ws + WS_ACC);
    k4_out_mfma<<<2048, 256, 0, stream>>>(cnh, cnl, woh, wol, (const int*)(ws + WS_IDX),
                                          b_out, out);
    k6_finalize<<<1, 1, 0, stream>>>(ws + WS_ACC, out + OUT_LOSS_OFF);
}